// Round 17
// baseline (1503.479 us; speedup 1.0000x reference)
//
#include <hip/hip_runtime.h>

#define TT 512
#define BB 1024
#define XD 24
#define ZD 16
#define MR 2          // valid batch rows per block

typedef __attribute__((ext_vector_type(2))) _Float16 h2t;
typedef __attribute__((ext_vector_type(4))) _Float16 half4;
typedef __attribute__((ext_vector_type(8))) _Float16 half8;
typedef __attribute__((ext_vector_type(4))) float f32x4;
typedef unsigned long long u64;

__device__ __forceinline__ f32x4 MFMA16(half4 a, half4 b, f32x4 c) {
#if defined(__HIP_DEVICE_COMPILE__)
    return __builtin_amdgcn_mfma_f32_16x16x16f16(a, b, c, 0, 0, 0);
#else
    return c;   // host pass only needs to parse
#endif
}
__device__ __forceinline__ f32x4 MFMA32(half8 a, half8 b, f32x4 c) {
#if defined(__HIP_DEVICE_COMPILE__)
    return __builtin_amdgcn_mfma_f32_16x16x32_f16(a, b, c, 0, 0, 0);
#else
    return c;
#endif
}

__device__ __forceinline__ float rcpf(float x) {
#if defined(__HIP_DEVICE_COMPILE__)
    return __builtin_amdgcn_rcpf(x);
#else
    return 1.0f / x;
#endif
}

__device__ __forceinline__ h2t pkrtz(float a, float b) {
#if defined(__HIP_DEVICE_COMPILE__)
    union { __attribute__((ext_vector_type(2))) __fp16 f; h2t h; } c;
    c.f = __builtin_amdgcn_cvt_pkrtz(a, b);
    return c.h;
#else
    h2t r; r[0] = (_Float16)a; r[1] = (_Float16)b; return r;
#endif
}

// Raw barrier: waits LDS ops only; global prefetch loads stay in flight.
#define BAR() asm volatile("s_waitcnt lgkmcnt(0)\n\ts_barrier" ::: "memory")

__device__ __forceinline__ f32x4 Z4() { return (f32x4){0.f, 0.f, 0.f, 0.f}; }

__device__ __forceinline__ float sigm(float x) { return rcpf(1.0f + __expf(-x)); }

__device__ __forceinline__ float tanh_fast(float x) {
    return 1.0f - 2.0f * rcpf(1.0f + __expf(2.0f * x));   // saturates via inf/rcp
}

__device__ __forceinline__ float softplus_f(float x) {
    return fmaxf(x, 0.0f) + __logf(1.0f + __expf(-fabsf(x)));
}

// x16 A-frag of W^T: lane holds W[k0+(l>>4)*4+j][o0+(l&15)], j=0..3
__device__ __forceinline__ half4 ldw(const float* W, int N, int Kreal, int Nreal,
                                     int k0, int o0, int lane) {
    int col = o0 + (lane & 15);
    int kb = k0 + ((lane >> 4) << 2);
    half4 r;
#pragma unroll
    for (int j = 0; j < 4; ++j) {
        int k = kb + j;
        float v = (k < Kreal && col < Nreal) ? W[(size_t)k * N + col] : 0.0f;
        r[j] = (_Float16)v;
    }
    return r;
}
// x32 A-frag of W^T: lane holds W[k0+(l>>4)*8+j][o0+(l&15)], j=0..7
__device__ __forceinline__ half8 ldw32(const float* W, int N, int Kreal, int Nreal,
                                       int k0, int o0, int lane) {
    int col = o0 + (lane & 15);
    int kb = k0 + ((lane >> 4) << 3);
    half8 r;
#pragma unroll
    for (int j = 0; j < 8; ++j) {
        int k = kb + j;
        float v = (k < Kreal && col < Nreal) ? W[(size_t)k * N + col] : 0.0f;
        r[j] = (_Float16)v;
    }
    return r;
}

// Packed RTZ: relu + convert
__device__ __forceinline__ half4 cvt_relu(f32x4 a) {
    union { h2t p[2]; half4 h; } c;
    c.p[0] = pkrtz(fmaxf(a[0], 0.f), fmaxf(a[1], 0.f));
    c.p[1] = pkrtz(fmaxf(a[2], 0.f), fmaxf(a[3], 0.f));
    return c.h;
}
__device__ __forceinline__ half4 cvt4(f32x4 a) {
    union { h2t p[2]; half4 h; } c;
    c.p[0] = pkrtz(a[0], a[1]);
    c.p[1] = pkrtz(a[2], a[3]);
    return c.h;
}
// RNE scalar convert (recurrent h)
__device__ __forceinline__ half4 cvt4_rne(f32x4 a) {
    half4 r;
#pragma unroll
    for (int q = 0; q < 4; ++q) r[q] = (_Float16)a[q];
    return r;
}
// x input fragment: elems 0..7 = x[8*lgr .. 8*lgr+7]
__device__ __forceinline__ half8 xfrag(f32x4 A, f32x4 B) {
    union { h2t p[4]; half8 h; } c;
    c.p[0] = pkrtz(A[0], A[1]); c.p[1] = pkrtz(A[2], A[3]);
    c.p[2] = pkrtz(B[0], B[1]); c.p[3] = pkrtz(B[2], B[3]);
    return c.h;
}

__device__ __forceinline__ f32x4 ldb4(const float* b, int o, int lgr) {
    return *reinterpret_cast<const f32x4*>(b + o * 16 + lgr * 4);
}

__device__ __forceinline__ u64 h2u(half4 h) {
    union { half4 h; u64 u; } c; c.h = h; return c.u;
}

// Paired LDS layout: word w (= feature rows 4w..4w+3), col c lives at
// byte (w>>1)*256 + c*16 + (w&1)*8 — so pair p (rows 8p..8p+7) is one b128.
__device__ __forceinline__ void st_pair(u64* B, int w, int c, u64 v) {
    *reinterpret_cast<u64*>(reinterpret_cast<char*>(B) + ((w >> 1) * 256 + c * 16 + (w & 1) * 8)) = v;
}
__device__ __forceinline__ half8 ld_pair(const u64* B, int pair, int c) {
    return *reinterpret_cast<const half8*>(reinterpret_cast<const char*>(B) + pair * 256 + c * 16);
}

__global__ __launch_bounds__(256, 1) void vrnn_kernel(
    const float* __restrict__ src, const float* __restrict__ eps,
    const float* __restrict__ Wx1, const float* __restrict__ bx1,
    const float* __restrict__ Wx2, const float* __restrict__ bx2,
    const float* __restrict__ Wz,  const float* __restrict__ bz,
    const float* __restrict__ We1, const float* __restrict__ be1,
    const float* __restrict__ We2, const float* __restrict__ be2,
    const float* __restrict__ Wem, const float* __restrict__ bem,
    const float* __restrict__ Wes, const float* __restrict__ bes,
    const float* __restrict__ Wih, const float* __restrict__ Whh,
    const float* __restrict__ Wf1, const float* __restrict__ bf1,
    const float* __restrict__ Wf2, const float* __restrict__ bf2,
    const float* __restrict__ Wf3, const float* __restrict__ bf3,
    float* __restrict__ out)
{
    __shared__ alignas(16) u64 AXB[256];     // ax(t+1)
    __shared__ alignas(16) u64 A1B[256];     // a1(t)  (also prologue temp)
    __shared__ alignas(16) u64 HB[256];      // h
    __shared__ alignas(16) u64 PXB[2][256];  // phi_x, double-buffered

    const int tid = threadIdx.x;
    const int ws = tid >> 6;       // wave id = o-tile slice
    const int lane = tid & 63;
    const int lcol = lane & 15;    // batch column (only 0..MR-1 valid)
    const int lgr = lane >> 4;
    const int r0 = blockIdx.x * MR;
    const int o0w = ws * 16;
    const int wsl = ws * 4 + lgr;  // this lane's exchange word index
    const int myrow = r0 + (lcol & (MR - 1));   // clamped source row (always valid)

    // ---------------- weights ----------------
    half8 wx1w = ldw32(Wx1, 64, 24, 64, 0, o0w, lane);
    half8 wx2w[2], we1w[4], we2w[4][2];
#pragma unroll
    for (int kt = 0; kt < 2; ++kt) wx2w[kt] = ldw32(Wx2, 64, 64, 64, kt * 32, o0w, lane);
#pragma unroll
    for (int kt = 0; kt < 4; ++kt) we1w[kt] = ldw32(We1, 64, 128, 64, kt * 32, o0w, lane);
#pragma unroll
    for (int o = 0; o < 4; ++o)
#pragma unroll
        for (int kt = 0; kt < 2; ++kt) we2w[o][kt] = ldw32(We2, 64, 64, 64, kt * 32, o * 16, lane);
    half4 wemf[4], wesf[4], wzf4[4];
#pragma unroll
    for (int kt = 0; kt < 4; ++kt) {
        wemf[kt] = ldw(Wem, 16, 64, 16, kt * 16, 0, lane);
        wesf[kt] = ldw(Wes, 16, 64, 16, kt * 16, 0, lane);
    }
#pragma unroll
    for (int o = 0; o < 4; ++o) wzf4[o] = ldw(Wz, 64, 16, 64, 0, o * 16, lane);
    half8 wihw[3][2], whhw[3][2];
    half4 wihz[3][4];
#pragma unroll
    for (int g = 0; g < 3; ++g) {
#pragma unroll
        for (int kt = 0; kt < 2; ++kt) {
            wihw[g][kt] = ldw32(Wih, 192, 128, 192, kt * 32, g * 64 + o0w, lane);
            whhw[g][kt] = ldw32(Whh, 192, 64, 192, kt * 32, g * 64 + o0w, lane);
        }
#pragma unroll
        for (int kt = 0; kt < 4; ++kt)
            wihz[g][kt] = ldw(Wih, 192, 128, 192, 64 + kt * 16, g * 64 + o0w, lane);
    }
    const f32x4 B1 = ldb4(bx1, ws, lgr), B2 = ldb4(bx2, ws, lgr);
    const f32x4 BE1 = ldb4(be1, ws, lgr);
    f32x4 BE2f[4], BZf[4];
#pragma unroll
    for (int o = 0; o < 4; ++o) {
        BE2f[o] = ldb4(be2, o, lgr);
        BZf[o] = ldb4(bz, o, lgr);
    }
    const f32x4 BM = ldb4(bem, 0, lgr), BS = ldb4(bes, 0, lgr);

    const float* xb_ = src + (size_t)myrow * TT * XD;
    const float* eb_ = eps + (size_t)myrow * TT * ZD;
    float* po = out + BB + (size_t)(r0 + lcol) * 64;   // only deref'd when lcol < MR

    // ---------------- prologue ----------------
    f32x4 fxA = Z4(), fxB = Z4();
    if (lgr < 3) {
        fxA = *reinterpret_cast<const f32x4*>(xb_ + lgr * 8);
        fxB = *reinterpret_cast<const f32x4*>(xb_ + lgr * 8 + 4);
    }
    {   // ax(0) -> A1B (temp)
        f32x4 s = MFMA32(wx1w, xfrag(fxA, fxB), B1);
        st_pair(A1B, wsl, lcol, h2u(cvt_relu(s)));
    }
    HB[tid] = 0ull;
    f32x4 hD = Z4();
    fxA = Z4(); fxB = Z4();
    if (lgr < 3) {
        fxA = *reinterpret_cast<const f32x4*>(xb_ + XD + lgr * 8);
        fxB = *reinterpret_cast<const f32x4*>(xb_ + XD + lgr * 8 + 4);
    }
    BAR();
    {   // s2: phi_x(0) -> PXB[0]
        half8 a1p0 = ld_pair(A1B, lgr, lcol);
        half8 a1p1 = ld_pair(A1B, 4 + lgr, lcol);
        f32x4 s = MFMA32(wx2w[1], a1p1, MFMA32(wx2w[0], a1p0, B2));
        st_pair(PXB[0], wsl, lcol, h2u(cvt_relu(s)));
    }
    f32x4 fe = *reinterpret_cast<const f32x4*>(eb_ + lgr * 4);
    BAR();

    half4 pzb[4];
    half8 pxp0, pxp1;

#pragma unroll 1
    for (int t = 0; t < TT; ++t) {
        const int cur = t & 1, nxt = cur ^ 1;
        const size_t t1 = (size_t)((t + 1) & (TT - 1));
        const size_t t2 = (size_t)((t + 2) & (TT - 1));

        // ================= P1: s3 + gh + s1(t+1) =================
        half8 hp0 = ld_pair(HB, lgr, lcol);
        half8 hp1 = ld_pair(HB, 4 + lgr, lcol);
        pxp0 = ld_pair(PXB[cur], lgr, lcol);
        pxp1 = ld_pair(PXB[cur], 4 + lgr, lcol);

        {   // s3: a1 o-tile ws (K=128: px 0..63, h 64..127)
            f32x4 a = MFMA32(we1w[1], pxp1, MFMA32(we1w[0], pxp0, BE1));
            f32x4 b = MFMA32(we1w[3], hp1, MFMA32(we1w[2], hp0, Z4()));
            st_pair(A1B, wsl, lcol, h2u(cvt_relu(a + b)));
        }
        f32x4 ga[3];
#pragma unroll
        for (int g = 0; g < 3; ++g)   // gh for r,u,n (col-slice ws)
            ga[g] = MFMA32(whhw[g][1], hp1, MFMA32(whhw[g][0], hp0, Z4()));
        {   // s1(t+1) -> AXB; garbage at t=TT-1 never read
            f32x4 s = MFMA32(wx1w, xfrag(fxA, fxB), B1);
            st_pair(AXB, wsl, lcol, h2u(cvt_relu(s)));
            fxA = Z4(); fxB = Z4();
            if (lgr < 3) {
                fxA = *reinterpret_cast<const f32x4*>(xb_ + t2 * XD + lgr * 8);
                fxB = *reinterpret_cast<const f32x4*>(xb_ + t2 * XD + lgr * 8 + 4);
            }
        }
        BAR();

        // ============ P2: s4 + s5 + z + s6-full + GRU + h + s2(t+1) =====================
        half8 a1p0 = ld_pair(A1B, lgr, lcol);
        half8 a1p1 = ld_pair(A1B, 4 + lgr, lcol);
        half8 axp0 = ld_pair(AXB, lgr, lcol);
        half8 axp1 = ld_pair(AXB, 4 + lgr, lcol);

        half4 enb[4];
#pragma unroll
        for (int o = 0; o < 4; ++o)
            enb[o] = cvt_relu(MFMA32(we2w[o][1], a1p1, MFMA32(we2w[o][0], a1p0, BE2f[o])));

        f32x4 am = MFMA16(wemf[1], enb[1], MFMA16(wemf[0], enb[0], BM));
        f32x4 am2 = MFMA16(wemf[3], enb[3], MFMA16(wemf[2], enb[2], Z4()));
        f32x4 as_ = MFMA16(wesf[1], enb[1], MFMA16(wesf[0], enb[0], BS));
        f32x4 as2 = MFMA16(wesf[3], enb[3], MFMA16(wesf[2], enb[2], Z4()));
        f32x4 eC = fe;
        fe = *reinterpret_cast<const f32x4*>(eb_ + t1 * ZD + lgr * 4);
        f32x4 zD;
#pragma unroll
        for (int q = 0; q < 4; ++q)
            zD[q] = eC[q] * softplus_f(as_[q] + as2[q]) + (am[q] + am2[q]);
        half4 zb = cvt4(zD);

        // s6-full: phi_z all o-tiles in-register (x16 D≡B feeds gi)
#pragma unroll
        for (int o = 0; o < 4; ++o) {
            f32x4 a = MFMA16(wzf4[o], zb, BZf[o]);
            if (t == TT - 1 && ws == 0 && lcol < MR) {
                f32x4 pr;
#pragma unroll
                for (int q = 0; q < 4; ++q) pr[q] = fmaxf(a[q], 0.0f);
                *reinterpret_cast<f32x4*>(po + o * 16 + lgr * 4) = pr;
            }
            pzb[o] = cvt_relu(a);
        }

        // GRU gates (col-slice ws): px-half x32 (from P1 regs), pz-half x16
        f32x4 gi[3];
#pragma unroll
        for (int g = 0; g < 3; ++g) {
            f32x4 p = MFMA32(wihw[g][1], pxp1, MFMA32(wihw[g][0], pxp0, (g < 2) ? ga[g] : Z4()));
            f32x4 q = MFMA16(wihz[g][1], pzb[1], MFMA16(wihz[g][0], pzb[0], Z4()));
            f32x4 q2 = MFMA16(wihz[g][3], pzb[3], MFMA16(wihz[g][2], pzb[2], Z4()));
            gi[g] = p + (q + q2);
        }
#pragma unroll
        for (int q = 0; q < 4; ++q) {
            float rr = sigm(gi[0][q]);
            float uu = sigm(gi[1][q]);
            float nn = tanh_fast(gi[2][q] + rr * ga[2][q]);
            hD[q] = nn + uu * (hD[q] - nn);
        }
        st_pair(HB, wsl, lcol, h2u(cvt4_rne(hD)));

        {   // s2(t+1) -> PXB[nxt]
            f32x4 s = MFMA32(wx2w[1], axp1, MFMA32(wx2w[0], axp0, B2));
            st_pair(PXB[nxt], wsl, lcol, h2u(cvt_relu(s)));
        }
        BAR();
    }

    // ---------------- regressor head (wave 0; pzb held in registers) ----------------
    if (ws == 0) {
        half4 wf1t[4][4], wf2t[2][4], wf3t[2];
#pragma unroll
        for (int o = 0; o < 4; ++o)
#pragma unroll
            for (int kt = 0; kt < 4; ++kt) wf1t[o][kt] = ldw(Wf1, 64, 64, 64, kt * 16, o * 16, lane);
#pragma unroll
        for (int o = 0; o < 2; ++o)
#pragma unroll
            for (int kt = 0; kt < 4; ++kt) wf2t[o][kt] = ldw(Wf2, 32, 64, 32, kt * 16, o * 16, lane);
        wf3t[0] = ldw(Wf3, 1, 32, 1, 0, 0, lane);
        wf3t[1] = ldw(Wf3, 1, 32, 1, 16, 0, lane);

        half4 o1b[4];
#pragma unroll
        for (int o = 0; o < 4; ++o) {
            f32x4 a = ldb4(bf1, o, lgr);
#pragma unroll
            for (int kt = 0; kt < 4; ++kt) a = MFMA16(wf1t[o][kt], pzb[kt], a);
            o1b[o] = cvt_relu(a);
        }
        half4 o2b[2];
#pragma unroll
        for (int o = 0; o < 2; ++o) {
            f32x4 a = ldb4(bf2, o, lgr);
#pragma unroll
            for (int kt = 0; kt < 4; ++kt) a = MFMA16(wf2t[o][kt], o1b[kt], a);
            o2b[o] = cvt_relu(a);
        }
        float b3 = bf3[0];
        f32x4 p = (f32x4){b3, b3, b3, b3};
        p = MFMA16(wf3t[0], o2b[0], p);
        p = MFMA16(wf3t[1], o2b[1], p);
        if (lgr == 0 && lcol < MR) out[r0 + lcol] = p[0];
    }
}

extern "C" void kernel_launch(void* const* d_in, const int* in_sizes, int n_in,
                              void* d_out, int out_size, void* d_ws, size_t ws_size,
                              hipStream_t stream) {
    (void)in_sizes; (void)n_in; (void)d_ws; (void)ws_size; (void)out_size;
    const float* src = (const float*)d_in[0];
    const float* eps = (const float*)d_in[1];
    const float* Wx1 = (const float*)d_in[2];
    const float* bx1 = (const float*)d_in[3];
    const float* Wx2 = (const float*)d_in[4];
    const float* bx2 = (const float*)d_in[5];
    const float* Wz  = (const float*)d_in[6];
    const float* bz  = (const float*)d_in[7];
    const float* We1 = (const float*)d_in[8];
    const float* be1 = (const float*)d_in[9];
    const float* We2 = (const float*)d_in[10];
    const float* be2 = (const float*)d_in[11];
    const float* Wem = (const float*)d_in[12];
    const float* bem = (const float*)d_in[13];
    const float* Wes = (const float*)d_in[14];
    const float* bes = (const float*)d_in[15];
    const float* Wih = (const float*)d_in[16];
    const float* Whh = (const float*)d_in[17];
    const float* Wf1 = (const float*)d_in[18];
    const float* bf1 = (const float*)d_in[19];
    const float* Wf2 = (const float*)d_in[20];
    const float* bf2 = (const float*)d_in[21];
    const float* Wf3 = (const float*)d_in[22];
    const float* bf3 = (const float*)d_in[23];
    float* out = (float*)d_out;

    hipLaunchKernelGGL(vrnn_kernel, dim3(BB / MR), dim3(256), 0, stream,
                       src, eps, Wx1, bx1, Wx2, bx2, Wz, bz, We1, be1, We2, be2,
                       Wem, bem, Wes, bes, Wih, Whh, Wf1, bf1, Wf2, bf2, Wf3, bf3, out);
}

// Round 18
// 813.221 us; speedup vs baseline: 1.8488x; 1.8488x over previous
//
#include <hip/hip_runtime.h>

#define TT 512
#define BB 1024
#define XD 24
#define ZD 16

typedef __attribute__((ext_vector_type(2))) _Float16 h2t;
typedef __attribute__((ext_vector_type(4))) _Float16 half4;
typedef __attribute__((ext_vector_type(8))) _Float16 half8;
typedef __attribute__((ext_vector_type(4))) float f32x4;
typedef unsigned long long u64;

__device__ __forceinline__ f32x4 MFMA16(half4 a, half4 b, f32x4 c) {
#if defined(__HIP_DEVICE_COMPILE__)
    return __builtin_amdgcn_mfma_f32_16x16x16f16(a, b, c, 0, 0, 0);
#else
    return c;   // host pass only needs to parse
#endif
}
__device__ __forceinline__ f32x4 MFMA32(half8 a, half8 b, f32x4 c) {
#if defined(__HIP_DEVICE_COMPILE__)
    return __builtin_amdgcn_mfma_f32_16x16x32_f16(a, b, c, 0, 0, 0);
#else
    return c;
#endif
}

__device__ __forceinline__ float rcpf(float x) {
#if defined(__HIP_DEVICE_COMPILE__)
    return __builtin_amdgcn_rcpf(x);
#else
    return 1.0f / x;
#endif
}

__device__ __forceinline__ h2t pkrtz(float a, float b) {
#if defined(__HIP_DEVICE_COMPILE__)
    union { __attribute__((ext_vector_type(2))) __fp16 f; h2t h; } c;
    c.f = __builtin_amdgcn_cvt_pkrtz(a, b);
    return c.h;
#else
    h2t r; r[0] = (_Float16)a; r[1] = (_Float16)b; return r;
#endif
}

// Raw barrier: waits LDS ops only; global prefetch loads stay in flight.
#define BAR() asm volatile("s_waitcnt lgkmcnt(0)\n\ts_barrier" ::: "memory")

__device__ __forceinline__ f32x4 Z4() { return (f32x4){0.f, 0.f, 0.f, 0.f}; }

__device__ __forceinline__ float sigm(float x) { return rcpf(1.0f + __expf(-x)); }

__device__ __forceinline__ float tanh_fast(float x) {
    return 1.0f - 2.0f * rcpf(1.0f + __expf(2.0f * x));   // saturates via inf/rcp
}

__device__ __forceinline__ float softplus_f(float x) {
    return fmaxf(x, 0.0f) + __logf(1.0f + __expf(-fabsf(x)));
}

// x16 A-frag of W^T: lane holds W[k0+(l>>4)*4+j][o0+(l&15)], j=0..3
__device__ __forceinline__ half4 ldw(const float* W, int N, int Kreal, int Nreal,
                                     int k0, int o0, int lane) {
    int col = o0 + (lane & 15);
    int kb = k0 + ((lane >> 4) << 2);
    half4 r;
#pragma unroll
    for (int j = 0; j < 4; ++j) {
        int k = kb + j;
        float v = (k < Kreal && col < Nreal) ? W[(size_t)k * N + col] : 0.0f;
        r[j] = (_Float16)v;
    }
    return r;
}
// x32 A-frag of W^T: lane holds W[k0+(l>>4)*8+j][o0+(l&15)], j=0..7
__device__ __forceinline__ half8 ldw32(const float* W, int N, int Kreal, int Nreal,
                                       int k0, int o0, int lane) {
    int col = o0 + (lane & 15);
    int kb = k0 + ((lane >> 4) << 3);
    half8 r;
#pragma unroll
    for (int j = 0; j < 8; ++j) {
        int k = kb + j;
        float v = (k < Kreal && col < Nreal) ? W[(size_t)k * N + col] : 0.0f;
        r[j] = (_Float16)v;
    }
    return r;
}

// Packed RTZ: relu + convert
__device__ __forceinline__ half4 cvt_relu(f32x4 a) {
    union { h2t p[2]; half4 h; } c;
    c.p[0] = pkrtz(fmaxf(a[0], 0.f), fmaxf(a[1], 0.f));
    c.p[1] = pkrtz(fmaxf(a[2], 0.f), fmaxf(a[3], 0.f));
    return c.h;
}
__device__ __forceinline__ half4 cvt4(f32x4 a) {
    union { h2t p[2]; half4 h; } c;
    c.p[0] = pkrtz(a[0], a[1]);
    c.p[1] = pkrtz(a[2], a[3]);
    return c.h;
}
// RNE scalar convert (recurrent h)
__device__ __forceinline__ half4 cvt4_rne(f32x4 a) {
    half4 r;
#pragma unroll
    for (int q = 0; q < 4; ++q) r[q] = (_Float16)a[q];
    return r;
}
// x input fragment: elems 0..7 = x[8*lgr .. 8*lgr+7]
__device__ __forceinline__ half8 xfrag(f32x4 A, f32x4 B) {
    union { h2t p[4]; half8 h; } c;
    c.p[0] = pkrtz(A[0], A[1]); c.p[1] = pkrtz(A[2], A[3]);
    c.p[2] = pkrtz(B[0], B[1]); c.p[3] = pkrtz(B[2], B[3]);
    return c.h;
}

__device__ __forceinline__ f32x4 ldb4(const float* b, int o, int lgr) {
    return *reinterpret_cast<const f32x4*>(b + o * 16 + lgr * 4);
}

__device__ __forceinline__ u64 h2u(half4 h) {
    union { half4 h; u64 u; } c; c.h = h; return c.u;
}

// Paired LDS layout: word w (= feature rows 4w..4w+3), col c lives at
// byte (w>>1)*256 + c*16 + (w&1)*8 — so pair p (rows 8p..8p+7) is one b128.
__device__ __forceinline__ void st_pair(u64* B, int w, int c, u64 v) {
    *reinterpret_cast<u64*>(reinterpret_cast<char*>(B) + ((w >> 1) * 256 + c * 16 + (w & 1) * 8)) = v;
}
__device__ __forceinline__ half8 ld_pair(const u64* B, int pair, int c) {
    return *reinterpret_cast<const half8*>(reinterpret_cast<const char*>(B) + pair * 256 + c * 16);
}

__global__ __launch_bounds__(256, 1) void vrnn_kernel(
    const float* __restrict__ src, const float* __restrict__ eps,
    const float* __restrict__ Wx1, const float* __restrict__ bx1,
    const float* __restrict__ Wx2, const float* __restrict__ bx2,
    const float* __restrict__ Wz,  const float* __restrict__ bz,
    const float* __restrict__ We1, const float* __restrict__ be1,
    const float* __restrict__ We2, const float* __restrict__ be2,
    const float* __restrict__ Wem, const float* __restrict__ bem,
    const float* __restrict__ Wes, const float* __restrict__ bes,
    const float* __restrict__ Wih, const float* __restrict__ Whh,
    const float* __restrict__ Wf1, const float* __restrict__ bf1,
    const float* __restrict__ Wf2, const float* __restrict__ bf2,
    const float* __restrict__ Wf3, const float* __restrict__ bf3,
    float* __restrict__ out)
{
    __shared__ alignas(16) u64 AXB[256];     // ax(t+1)
    __shared__ alignas(16) u64 A1B[256];     // a1(t)  (also prologue temp)
    __shared__ alignas(16) u64 HB[256];      // h
    __shared__ alignas(16) u64 PXB[2][256];  // phi_x, double-buffered

    const int tid = threadIdx.x;
    const int ws = tid >> 6;       // wave id = o-tile slice
    const int lane = tid & 63;
    const int lcol = lane & 15;    // batch column
    const int lgr = lane >> 4;
    const int r0 = blockIdx.x * 16;
    const int o0w = ws * 16;
    const int wsl = ws * 4 + lgr;  // this lane's exchange word index

    // ---------------- weights ----------------
    half8 wx1w = ldw32(Wx1, 64, 24, 64, 0, o0w, lane);
    half8 wx2w[2], we1w[4], we2w[4][2];
#pragma unroll
    for (int kt = 0; kt < 2; ++kt) wx2w[kt] = ldw32(Wx2, 64, 64, 64, kt * 32, o0w, lane);
#pragma unroll
    for (int kt = 0; kt < 4; ++kt) we1w[kt] = ldw32(We1, 64, 128, 64, kt * 32, o0w, lane);
#pragma unroll
    for (int o = 0; o < 4; ++o)
#pragma unroll
        for (int kt = 0; kt < 2; ++kt) we2w[o][kt] = ldw32(We2, 64, 64, 64, kt * 32, o * 16, lane);
    half4 wemf[4], wesf[4], wzf4[4];
#pragma unroll
    for (int kt = 0; kt < 4; ++kt) {
        wemf[kt] = ldw(Wem, 16, 64, 16, kt * 16, 0, lane);
        wesf[kt] = ldw(Wes, 16, 64, 16, kt * 16, 0, lane);
    }
#pragma unroll
    for (int o = 0; o < 4; ++o) wzf4[o] = ldw(Wz, 64, 16, 64, 0, o * 16, lane);
    half8 wihw[3][2], whhw[3][2];
    half4 wihz[3][4];
#pragma unroll
    for (int g = 0; g < 3; ++g) {
#pragma unroll
        for (int kt = 0; kt < 2; ++kt) {
            wihw[g][kt] = ldw32(Wih, 192, 128, 192, kt * 32, g * 64 + o0w, lane);
            whhw[g][kt] = ldw32(Whh, 192, 64, 192, kt * 32, g * 64 + o0w, lane);
        }
#pragma unroll
        for (int kt = 0; kt < 4; ++kt)
            wihz[g][kt] = ldw(Wih, 192, 128, 192, 64 + kt * 16, g * 64 + o0w, lane);
    }
    const f32x4 B1 = ldb4(bx1, ws, lgr), B2 = ldb4(bx2, ws, lgr);
    const f32x4 BE1 = ldb4(be1, ws, lgr);
    f32x4 BE2f[4], BZf[4];
#pragma unroll
    for (int o = 0; o < 4; ++o) {
        BE2f[o] = ldb4(be2, o, lgr);
        BZf[o] = ldb4(bz, o, lgr);
    }
    const f32x4 BM = ldb4(bem, 0, lgr), BS = ldb4(bes, 0, lgr);

    const float* xb_ = src + (size_t)(r0 + lcol) * TT * XD;
    const float* eb_ = eps + (size_t)(r0 + lcol) * TT * ZD;
    float* po = out + BB + (size_t)(r0 + lcol) * 64;

    // ---------------- prologue ----------------
    f32x4 fxA = Z4(), fxB = Z4();
    if (lgr < 3) {
        fxA = *reinterpret_cast<const f32x4*>(xb_ + lgr * 8);
        fxB = *reinterpret_cast<const f32x4*>(xb_ + lgr * 8 + 4);
    }
    {   // ax(0) -> A1B (temp)
        f32x4 s = MFMA32(wx1w, xfrag(fxA, fxB), B1);
        st_pair(A1B, wsl, lcol, h2u(cvt_relu(s)));
    }
    HB[tid] = 0ull;
    f32x4 hD = Z4();
    fxA = Z4(); fxB = Z4();
    if (lgr < 3) {
        fxA = *reinterpret_cast<const f32x4*>(xb_ + XD + lgr * 8);
        fxB = *reinterpret_cast<const f32x4*>(xb_ + XD + lgr * 8 + 4);
    }
    BAR();
    {   // s2: phi_x(0) -> PXB[0]
        half8 a1p0 = ld_pair(A1B, lgr, lcol);
        half8 a1p1 = ld_pair(A1B, 4 + lgr, lcol);
        f32x4 s = MFMA32(wx2w[1], a1p1, MFMA32(wx2w[0], a1p0, B2));
        st_pair(PXB[0], wsl, lcol, h2u(cvt_relu(s)));
    }
    f32x4 fe = *reinterpret_cast<const f32x4*>(eb_ + lgr * 4);
    BAR();

    half4 pzb[4];
    half8 pxp0, pxp1;

    // ============ unrolled 2-step body: CUR/NXT are compile-time constants ============
#define VRNN_STEP(T, CUR, NXT)                                                          \
    {                                                                                   \
        const int t = (T);                                                              \
        const size_t t1 = (size_t)((t + 1) & (TT - 1));                                 \
        const size_t t2 = (size_t)((t + 2) & (TT - 1));                                 \
        /* P1: s3 + gh + s1(t+1) */                                                     \
        half8 hp0 = ld_pair(HB, lgr, lcol);                                             \
        half8 hp1 = ld_pair(HB, 4 + lgr, lcol);                                         \
        pxp0 = ld_pair(PXB[CUR], lgr, lcol);                                            \
        pxp1 = ld_pair(PXB[CUR], 4 + lgr, lcol);                                        \
        {                                                                               \
            f32x4 a = MFMA32(we1w[1], pxp1, MFMA32(we1w[0], pxp0, BE1));                \
            f32x4 b = MFMA32(we1w[3], hp1, MFMA32(we1w[2], hp0, Z4()));                 \
            st_pair(A1B, wsl, lcol, h2u(cvt_relu(a + b)));                              \
        }                                                                               \
        f32x4 ga[3];                                                                    \
        _Pragma("unroll")                                                               \
        for (int g = 0; g < 3; ++g)                                                     \
            ga[g] = MFMA32(whhw[g][1], hp1, MFMA32(whhw[g][0], hp0, Z4()));             \
        {                                                                               \
            f32x4 s = MFMA32(wx1w, xfrag(fxA, fxB), B1);                                \
            st_pair(AXB, wsl, lcol, h2u(cvt_relu(s)));                                  \
            fxA = Z4(); fxB = Z4();                                                     \
            if (lgr < 3) {                                                              \
                fxA = *reinterpret_cast<const f32x4*>(xb_ + t2 * XD + lgr * 8);         \
                fxB = *reinterpret_cast<const f32x4*>(xb_ + t2 * XD + lgr * 8 + 4);     \
            }                                                                           \
        }                                                                               \
        BAR();                                                                          \
        /* P2: s4 + s5 + z + s6-full + GRU + h + s2(t+1) */                             \
        half8 a1p0 = ld_pair(A1B, lgr, lcol);                                           \
        half8 a1p1 = ld_pair(A1B, 4 + lgr, lcol);                                       \
        half8 axp0 = ld_pair(AXB, lgr, lcol);                                           \
        half8 axp1 = ld_pair(AXB, 4 + lgr, lcol);                                       \
        half4 enb[4];                                                                   \
        _Pragma("unroll")                                                               \
        for (int o = 0; o < 4; ++o)                                                     \
            enb[o] = cvt_relu(MFMA32(we2w[o][1], a1p1, MFMA32(we2w[o][0], a1p0, BE2f[o]))); \
        f32x4 am = MFMA16(wemf[1], enb[1], MFMA16(wemf[0], enb[0], BM));                \
        f32x4 am2 = MFMA16(wemf[3], enb[3], MFMA16(wemf[2], enb[2], Z4()));             \
        f32x4 as_ = MFMA16(wesf[1], enb[1], MFMA16(wesf[0], enb[0], BS));               \
        f32x4 as2 = MFMA16(wesf[3], enb[3], MFMA16(wesf[2], enb[2], Z4()));             \
        f32x4 eC = fe;                                                                  \
        fe = *reinterpret_cast<const f32x4*>(eb_ + t1 * ZD + lgr * 4);                  \
        f32x4 zD;                                                                       \
        _Pragma("unroll")                                                               \
        for (int q = 0; q < 4; ++q)                                                     \
            zD[q] = eC[q] * softplus_f(as_[q] + as2[q]) + (am[q] + am2[q]);             \
        half4 zb = cvt4(zD);                                                            \
        _Pragma("unroll")                                                               \
        for (int o = 0; o < 4; ++o) {                                                   \
            f32x4 a = MFMA16(wzf4[o], zb, BZf[o]);                                      \
            if (t == TT - 1 && ws == 0) {                                               \
                f32x4 pr;                                                               \
                _Pragma("unroll")                                                       \
                for (int q = 0; q < 4; ++q) pr[q] = fmaxf(a[q], 0.0f);                  \
                *reinterpret_cast<f32x4*>(po + o * 16 + lgr * 4) = pr;                  \
            }                                                                           \
            pzb[o] = cvt_relu(a);                                                       \
        }                                                                               \
        f32x4 gi[3];                                                                    \
        _Pragma("unroll")                                                               \
        for (int g = 0; g < 3; ++g) {                                                   \
            f32x4 p = MFMA32(wihw[g][1], pxp1, MFMA32(wihw[g][0], pxp0, (g < 2) ? ga[g] : Z4())); \
            f32x4 q = MFMA16(wihz[g][1], pzb[1], MFMA16(wihz[g][0], pzb[0], Z4()));     \
            f32x4 q2 = MFMA16(wihz[g][3], pzb[3], MFMA16(wihz[g][2], pzb[2], Z4()));    \
            gi[g] = p + (q + q2);                                                       \
        }                                                                               \
        _Pragma("unroll")                                                               \
        for (int q = 0; q < 4; ++q) {                                                   \
            float rr = sigm(gi[0][q]);                                                  \
            float uu = sigm(gi[1][q]);                                                  \
            float nn = tanh_fast(gi[2][q] + rr * ga[2][q]);                             \
            hD[q] = nn + uu * (hD[q] - nn);                                             \
        }                                                                               \
        st_pair(HB, wsl, lcol, h2u(cvt4_rne(hD)));                                      \
        {                                                                               \
            f32x4 s = MFMA32(wx2w[1], axp1, MFMA32(wx2w[0], axp0, B2));                 \
            st_pair(PXB[NXT], wsl, lcol, h2u(cvt_relu(s)));                             \
        }                                                                               \
        BAR();                                                                          \
    }

#pragma unroll 1
    for (int tt = 0; tt < TT; tt += 2) {
        VRNN_STEP(tt, 0, 1)
        VRNN_STEP(tt + 1, 1, 0)
    }
#undef VRNN_STEP

    // ---------------- regressor head (wave 0; pzb held in registers) ----------------
    if (ws == 0) {
        half4 wf1t[4][4], wf2t[2][4], wf3t[2];
#pragma unroll
        for (int o = 0; o < 4; ++o)
#pragma unroll
            for (int kt = 0; kt < 4; ++kt) wf1t[o][kt] = ldw(Wf1, 64, 64, 64, kt * 16, o * 16, lane);
#pragma unroll
        for (int o = 0; o < 2; ++o)
#pragma unroll
            for (int kt = 0; kt < 4; ++kt) wf2t[o][kt] = ldw(Wf2, 32, 64, 32, kt * 16, o * 16, lane);
        wf3t[0] = ldw(Wf3, 1, 32, 1, 0, 0, lane);
        wf3t[1] = ldw(Wf3, 1, 32, 1, 16, 0, lane);

        half4 o1b[4];
#pragma unroll
        for (int o = 0; o < 4; ++o) {
            f32x4 a = ldb4(bf1, o, lgr);
#pragma unroll
            for (int kt = 0; kt < 4; ++kt) a = MFMA16(wf1t[o][kt], pzb[kt], a);
            o1b[o] = cvt_relu(a);
        }
        half4 o2b[2];
#pragma unroll
        for (int o = 0; o < 2; ++o) {
            f32x4 a = ldb4(bf2, o, lgr);
#pragma unroll
            for (int kt = 0; kt < 4; ++kt) a = MFMA16(wf2t[o][kt], o1b[kt], a);
            o2b[o] = cvt_relu(a);
        }
        float b3 = bf3[0];
        f32x4 p = (f32x4){b3, b3, b3, b3};
        p = MFMA16(wf3t[0], o2b[0], p);
        p = MFMA16(wf3t[1], o2b[1], p);
        if (lgr == 0) out[r0 + lcol] = p[0];
    }
}

extern "C" void kernel_launch(void* const* d_in, const int* in_sizes, int n_in,
                              void* d_out, int out_size, void* d_ws, size_t ws_size,
                              hipStream_t stream) {
    (void)in_sizes; (void)n_in; (void)d_ws; (void)ws_size; (void)out_size;
    const float* src = (const float*)d_in[0];
    const float* eps = (const float*)d_in[1];
    const float* Wx1 = (const float*)d_in[2];
    const float* bx1 = (const float*)d_in[3];
    const float* Wx2 = (const float*)d_in[4];
    const float* bx2 = (const float*)d_in[5];
    const float* Wz  = (const float*)d_in[6];
    const float* bz  = (const float*)d_in[7];
    const float* We1 = (const float*)d_in[8];
    const float* be1 = (const float*)d_in[9];
    const float* We2 = (const float*)d_in[10];
    const float* be2 = (const float*)d_in[11];
    const float* Wem = (const float*)d_in[12];
    const float* bem = (const float*)d_in[13];
    const float* Wes = (const float*)d_in[14];
    const float* bes = (const float*)d_in[15];
    const float* Wih = (const float*)d_in[16];
    const float* Whh = (const float*)d_in[17];
    const float* Wf1 = (const float*)d_in[18];
    const float* bf1 = (const float*)d_in[19];
    const float* Wf2 = (const float*)d_in[20];
    const float* bf2 = (const float*)d_in[21];
    const float* Wf3 = (const float*)d_in[22];
    const float* bf3 = (const float*)d_in[23];
    float* out = (float*)d_out;

    hipLaunchKernelGGL(vrnn_kernel, dim3(BB / 16), dim3(256), 0, stream,
                       src, eps, Wx1, bx1, Wx2, bx2, Wz, bz, We1, be1, We2, be2,
                       Wem, bem, Wes, bes, Wih, Whh, Wf1, bf1, Wf2, bf2, Wf3, bf3, out);
}

// Round 19
// 759.945 us; speedup vs baseline: 1.9784x; 1.0701x over previous
//
#include <hip/hip_runtime.h>

#define TT 512
#define BB 1024
#define XD 24
#define ZD 16

typedef __attribute__((ext_vector_type(2))) _Float16 h2t;
typedef __attribute__((ext_vector_type(4))) _Float16 half4;
typedef __attribute__((ext_vector_type(8))) _Float16 half8;
typedef __attribute__((ext_vector_type(4))) float f32x4;
typedef unsigned long long u64;

__device__ __forceinline__ f32x4 MFMA16(half4 a, half4 b, f32x4 c) {
#if defined(__HIP_DEVICE_COMPILE__)
    return __builtin_amdgcn_mfma_f32_16x16x16f16(a, b, c, 0, 0, 0);
#else
    return c;   // host pass only needs to parse
#endif
}
__device__ __forceinline__ f32x4 MFMA32(half8 a, half8 b, f32x4 c) {
#if defined(__HIP_DEVICE_COMPILE__)
    return __builtin_amdgcn_mfma_f32_16x16x32_f16(a, b, c, 0, 0, 0);
#else
    return c;
#endif
}

__device__ __forceinline__ float rcpf(float x) {
#if defined(__HIP_DEVICE_COMPILE__)
    return __builtin_amdgcn_rcpf(x);
#else
    return 1.0f / x;
#endif
}

__device__ __forceinline__ h2t pkrtz(float a, float b) {
#if defined(__HIP_DEVICE_COMPILE__)
    union { __attribute__((ext_vector_type(2))) __fp16 f; h2t h; } c;
    c.f = __builtin_amdgcn_cvt_pkrtz(a, b);
    return c.h;
#else
    h2t r; r[0] = (_Float16)a; r[1] = (_Float16)b; return r;
#endif
}

// Raw barrier: waits LDS ops only; global prefetch loads stay in flight.
#define BAR() asm volatile("s_waitcnt lgkmcnt(0)\n\ts_barrier" ::: "memory")

__device__ __forceinline__ f32x4 Z4() { return (f32x4){0.f, 0.f, 0.f, 0.f}; }

__device__ __forceinline__ float sigm(float x) { return rcpf(1.0f + __expf(-x)); }

__device__ __forceinline__ float tanh_fast(float x) {
    return 1.0f - 2.0f * rcpf(1.0f + __expf(2.0f * x));   // saturates via inf/rcp
}

__device__ __forceinline__ float softplus_f(float x) {
    return fmaxf(x, 0.0f) + __logf(1.0f + __expf(-fabsf(x)));
}

// x16 A-frag of W^T: lane holds W[k0+(l>>4)*4+j][o0+(l&15)], j=0..3
__device__ __forceinline__ half4 ldw(const float* W, int N, int Kreal, int Nreal,
                                     int k0, int o0, int lane) {
    int col = o0 + (lane & 15);
    int kb = k0 + ((lane >> 4) << 2);
    half4 r;
#pragma unroll
    for (int j = 0; j < 4; ++j) {
        int k = kb + j;
        float v = (k < Kreal && col < Nreal) ? W[(size_t)k * N + col] : 0.0f;
        r[j] = (_Float16)v;
    }
    return r;
}
// x32 A-frag of W^T: lane holds W[k0+(l>>4)*8+j][o0+(l&15)], j=0..7
__device__ __forceinline__ half8 ldw32(const float* W, int N, int Kreal, int Nreal,
                                       int k0, int o0, int lane) {
    int col = o0 + (lane & 15);
    int kb = k0 + ((lane >> 4) << 3);
    half8 r;
#pragma unroll
    for (int j = 0; j < 8; ++j) {
        int k = kb + j;
        float v = (k < Kreal && col < Nreal) ? W[(size_t)k * N + col] : 0.0f;
        r[j] = (_Float16)v;
    }
    return r;
}

// Packed RTZ: relu + convert
__device__ __forceinline__ half4 cvt_relu(f32x4 a) {
    union { h2t p[2]; half4 h; } c;
    c.p[0] = pkrtz(fmaxf(a[0], 0.f), fmaxf(a[1], 0.f));
    c.p[1] = pkrtz(fmaxf(a[2], 0.f), fmaxf(a[3], 0.f));
    return c.h;
}
__device__ __forceinline__ half4 cvt4(f32x4 a) {
    union { h2t p[2]; half4 h; } c;
    c.p[0] = pkrtz(a[0], a[1]);
    c.p[1] = pkrtz(a[2], a[3]);
    return c.h;
}
// RNE scalar convert (recurrent h)
__device__ __forceinline__ half4 cvt4_rne(f32x4 a) {
    half4 r;
#pragma unroll
    for (int q = 0; q < 4; ++q) r[q] = (_Float16)a[q];
    return r;
}
// x input fragment: elems 0..7 = x[8*lgr .. 8*lgr+7]
__device__ __forceinline__ half8 xfrag(f32x4 A, f32x4 B) {
    union { h2t p[4]; half8 h; } c;
    c.p[0] = pkrtz(A[0], A[1]); c.p[1] = pkrtz(A[2], A[3]);
    c.p[2] = pkrtz(B[0], B[1]); c.p[3] = pkrtz(B[2], B[3]);
    return c.h;
}

__device__ __forceinline__ f32x4 ldb4(const float* b, int o, int lgr) {
    return *reinterpret_cast<const f32x4*>(b + o * 16 + lgr * 4);
}

__device__ __forceinline__ u64 h2u(half4 h) {
    union { half4 h; u64 u; } c; c.h = h; return c.u;
}

// Paired LDS layout: word w (= feature rows 4w..4w+3), col c lives at
// byte (w>>1)*256 + c*16 + (w&1)*8 — so pair p (rows 8p..8p+7) is one b128.
__device__ __forceinline__ void st_pair(u64* B, int w, int c, u64 v) {
    *reinterpret_cast<u64*>(reinterpret_cast<char*>(B) + ((w >> 1) * 256 + c * 16 + (w & 1) * 8)) = v;
}
__device__ __forceinline__ half8 ld_pair(const u64* B, int pair, int c) {
    return *reinterpret_cast<const half8*>(reinterpret_cast<const char*>(B) + pair * 256 + c * 16);
}

__global__ __launch_bounds__(256, 1) void vrnn_kernel(
    const float* __restrict__ src, const float* __restrict__ eps,
    const float* __restrict__ Wx1, const float* __restrict__ bx1,
    const float* __restrict__ Wx2, const float* __restrict__ bx2,
    const float* __restrict__ Wz,  const float* __restrict__ bz,
    const float* __restrict__ We1, const float* __restrict__ be1,
    const float* __restrict__ We2, const float* __restrict__ be2,
    const float* __restrict__ Wem, const float* __restrict__ bem,
    const float* __restrict__ Wes, const float* __restrict__ bes,
    const float* __restrict__ Wih, const float* __restrict__ Whh,
    const float* __restrict__ Wf1, const float* __restrict__ bf1,
    const float* __restrict__ Wf2, const float* __restrict__ bf2,
    const float* __restrict__ Wf3, const float* __restrict__ bf3,
    float* __restrict__ out)
{
    __shared__ alignas(16) u64 AXB[256];     // ax(t+1)
    __shared__ alignas(16) u64 A1B[256];     // a1(t)  (also prologue temp)
    __shared__ alignas(16) u64 HB[256];      // h
    __shared__ alignas(16) u64 PXB[2][256];  // phi_x, double-buffered

    const int tid = threadIdx.x;
    const int ws = tid >> 6;       // wave id = o-tile slice
    const int lane = tid & 63;
    const int lcol = lane & 15;    // batch column
    const int lgr = lane >> 4;
    const int r0 = blockIdx.x * 16;
    const int o0w = ws * 16;
    const int wsl = ws * 4 + lgr;  // this lane's exchange word index

    // ---------------- weights ----------------
    half8 wx1w = ldw32(Wx1, 64, 24, 64, 0, o0w, lane);
    half8 wx2w[2], we1w[4], we2w[4][2];
#pragma unroll
    for (int kt = 0; kt < 2; ++kt) wx2w[kt] = ldw32(Wx2, 64, 64, 64, kt * 32, o0w, lane);
#pragma unroll
    for (int kt = 0; kt < 4; ++kt) we1w[kt] = ldw32(We1, 64, 128, 64, kt * 32, o0w, lane);
#pragma unroll
    for (int o = 0; o < 4; ++o)
#pragma unroll
        for (int kt = 0; kt < 2; ++kt) we2w[o][kt] = ldw32(We2, 64, 64, 64, kt * 32, o * 16, lane);
    half4 wemf[4], wesf[4], wzf4[4];
#pragma unroll
    for (int kt = 0; kt < 4; ++kt) {
        wemf[kt] = ldw(Wem, 16, 64, 16, kt * 16, 0, lane);
        wesf[kt] = ldw(Wes, 16, 64, 16, kt * 16, 0, lane);
    }
#pragma unroll
    for (int o = 0; o < 4; ++o) wzf4[o] = ldw(Wz, 64, 16, 64, 0, o * 16, lane);
    half8 wihw[3][2], whhw[3][2];
    half4 wihz[3][4];
#pragma unroll
    for (int g = 0; g < 3; ++g) {
#pragma unroll
        for (int kt = 0; kt < 2; ++kt) {
            wihw[g][kt] = ldw32(Wih, 192, 128, 192, kt * 32, g * 64 + o0w, lane);
            whhw[g][kt] = ldw32(Whh, 192, 64, 192, kt * 32, g * 64 + o0w, lane);
        }
#pragma unroll
        for (int kt = 0; kt < 4; ++kt)
            wihz[g][kt] = ldw(Wih, 192, 128, 192, 64 + kt * 16, g * 64 + o0w, lane);
    }
    const f32x4 B1 = ldb4(bx1, ws, lgr), B2 = ldb4(bx2, ws, lgr);
    const f32x4 BE1 = ldb4(be1, ws, lgr);
    f32x4 BE2f[4], BZf[4];
#pragma unroll
    for (int o = 0; o < 4; ++o) {
        BE2f[o] = ldb4(be2, o, lgr);
        BZf[o] = ldb4(bz, o, lgr);
    }
    const f32x4 BM = ldb4(bem, 0, lgr), BS = ldb4(bes, 0, lgr);

    const float* xb_ = src + (size_t)(r0 + lcol) * TT * XD;
    const float* eb_ = eps + (size_t)(r0 + lcol) * TT * ZD;
    float* po = out + BB + (size_t)(r0 + lcol) * 64;

    // ---------------- prologue ----------------
    // fxA/fxB zeros set ONCE: lgr==3 lanes carry k-padding zeros for all 512 steps.
    f32x4 fxA = Z4(), fxB = Z4();
    if (lgr < 3) {
        fxA = *reinterpret_cast<const f32x4*>(xb_ + lgr * 8);
        fxB = *reinterpret_cast<const f32x4*>(xb_ + lgr * 8 + 4);
    }
    {   // ax(0) -> A1B (temp)
        f32x4 s = MFMA32(wx1w, xfrag(fxA, fxB), B1);
        st_pair(A1B, wsl, lcol, h2u(cvt_relu(s)));
    }
    HB[tid] = 0ull;
    f32x4 hD = Z4();
    if (lgr < 3) {
        fxA = *reinterpret_cast<const f32x4*>(xb_ + XD + lgr * 8);
        fxB = *reinterpret_cast<const f32x4*>(xb_ + XD + lgr * 8 + 4);
    }
    BAR();
    {   // s2: phi_x(0) -> PXB[0]
        half8 a1p0 = ld_pair(A1B, lgr, lcol);
        half8 a1p1 = ld_pair(A1B, 4 + lgr, lcol);
        f32x4 s = MFMA32(wx2w[1], a1p1, MFMA32(wx2w[0], a1p0, B2));
        st_pair(PXB[0], wsl, lcol, h2u(cvt_relu(s)));
    }
    f32x4 fe = *reinterpret_cast<const f32x4*>(eb_ + lgr * 4);
    BAR();

    half4 pzb[4];
    half8 pxp0, pxp1;

#pragma unroll 1
    for (int t = 0; t < TT; ++t) {
        const int cur = t & 1, nxt = cur ^ 1;
        const size_t t1 = (size_t)((t + 1) & (TT - 1));
        const size_t t2 = (size_t)((t + 2) & (TT - 1));

        // ================= P1: s3 + gh + s1(t+1) =================
        half8 hp0 = ld_pair(HB, lgr, lcol);
        half8 hp1 = ld_pair(HB, 4 + lgr, lcol);
        pxp0 = ld_pair(PXB[cur], lgr, lcol);
        pxp1 = ld_pair(PXB[cur], 4 + lgr, lcol);

        {   // s3: a1 o-tile ws — 4-deep chain (no vector adds)
            f32x4 a = MFMA32(we1w[3], hp1,
                      MFMA32(we1w[2], hp0,
                      MFMA32(we1w[1], pxp1,
                      MFMA32(we1w[0], pxp0, BE1))));
            st_pair(A1B, wsl, lcol, h2u(cvt_relu(a)));
        }
        f32x4 ga[3];
#pragma unroll
        for (int g = 0; g < 3; ++g)   // gh for r,u,n (col-slice ws)
            ga[g] = MFMA32(whhw[g][1], hp1, MFMA32(whhw[g][0], hp0, Z4()));
        {   // s1(t+1) -> AXB; garbage at t=TT-1 never read
            f32x4 s = MFMA32(wx1w, xfrag(fxA, fxB), B1);
            st_pair(AXB, wsl, lcol, h2u(cvt_relu(s)));
            if (lgr < 3) {
                fxA = *reinterpret_cast<const f32x4*>(xb_ + t2 * XD + lgr * 8);
                fxB = *reinterpret_cast<const f32x4*>(xb_ + t2 * XD + lgr * 8 + 4);
            }
        }
        BAR();

        // ============ P2: s4 + s5 + z + s6-full + GRU + h + s2(t+1) =====================
        half8 a1p0 = ld_pair(A1B, lgr, lcol);
        half8 a1p1 = ld_pair(A1B, 4 + lgr, lcol);
        half8 axp0 = ld_pair(AXB, lgr, lcol);
        half8 axp1 = ld_pair(AXB, 4 + lgr, lcol);

        half4 enb[4];
#pragma unroll
        for (int o = 0; o < 4; ++o)
            enb[o] = cvt_relu(MFMA32(we2w[o][1], a1p1, MFMA32(we2w[o][0], a1p0, BE2f[o])));

        // s5: 4-deep chains (no am2/as2 accumulators or merges)
        f32x4 am = MFMA16(wemf[3], enb[3],
                   MFMA16(wemf[2], enb[2],
                   MFMA16(wemf[1], enb[1],
                   MFMA16(wemf[0], enb[0], BM))));
        f32x4 as_ = MFMA16(wesf[3], enb[3],
                    MFMA16(wesf[2], enb[2],
                    MFMA16(wesf[1], enb[1],
                    MFMA16(wesf[0], enb[0], BS))));
        f32x4 eC = fe;
        fe = *reinterpret_cast<const f32x4*>(eb_ + t1 * ZD + lgr * 4);
        f32x4 zD;
#pragma unroll
        for (int q = 0; q < 4; ++q)
            zD[q] = eC[q] * softplus_f(as_[q]) + am[q];
        half4 zb = cvt4(zD);

        // s6-full: phi_z all o-tiles in-register (x16 D≡B feeds gi)
#pragma unroll
        for (int o = 0; o < 4; ++o) {
            f32x4 a = MFMA16(wzf4[o], zb, BZf[o]);
            if (t == TT - 1 && ws == 0) {
                f32x4 pr;
#pragma unroll
                for (int q = 0; q < 4; ++q) pr[q] = fmaxf(a[q], 0.0f);
                *reinterpret_cast<f32x4*>(po + o * 16 + lgr * 4) = pr;
            }
            pzb[o] = cvt_relu(a);
        }

        // GRU gates (col-slice ws): single 6-deep chain per gate (no vector adds)
        f32x4 gi[3];
#pragma unroll
        for (int g = 0; g < 3; ++g) {
            gi[g] = MFMA16(wihz[g][3], pzb[3],
                    MFMA16(wihz[g][2], pzb[2],
                    MFMA16(wihz[g][1], pzb[1],
                    MFMA16(wihz[g][0], pzb[0],
                    MFMA32(wihw[g][1], pxp1,
                    MFMA32(wihw[g][0], pxp0, (g < 2) ? ga[g] : Z4()))))));
        }
#pragma unroll
        for (int q = 0; q < 4; ++q) {
            float rr = sigm(gi[0][q]);
            float uu = sigm(gi[1][q]);
            float nn = tanh_fast(gi[2][q] + rr * ga[2][q]);
            hD[q] = nn + uu * (hD[q] - nn);
        }
        st_pair(HB, wsl, lcol, h2u(cvt4_rne(hD)));

        {   // s2(t+1) -> PXB[nxt]
            f32x4 s = MFMA32(wx2w[1], axp1, MFMA32(wx2w[0], axp0, B2));
            st_pair(PXB[nxt], wsl, lcol, h2u(cvt_relu(s)));
        }
        BAR();
    }

    // ---------------- regressor head (wave 0; pzb held in registers) ----------------
    if (ws == 0) {
        half4 wf1t[4][4], wf2t[2][4], wf3t[2];
#pragma unroll
        for (int o = 0; o < 4; ++o)
#pragma unroll
            for (int kt = 0; kt < 4; ++kt) wf1t[o][kt] = ldw(Wf1, 64, 64, 64, kt * 16, o * 16, lane);
#pragma unroll
        for (int o = 0; o < 2; ++o)
#pragma unroll
            for (int kt = 0; kt < 4; ++kt) wf2t[o][kt] = ldw(Wf2, 32, 64, 32, kt * 16, o * 16, lane);
        wf3t[0] = ldw(Wf3, 1, 32, 1, 0, 0, lane);
        wf3t[1] = ldw(Wf3, 1, 32, 1, 16, 0, lane);

        half4 o1b[4];
#pragma unroll
        for (int o = 0; o < 4; ++o) {
            f32x4 a = ldb4(bf1, o, lgr);
#pragma unroll
            for (int kt = 0; kt < 4; ++kt) a = MFMA16(wf1t[o][kt], pzb[kt], a);
            o1b[o] = cvt_relu(a);
        }
        half4 o2b[2];
#pragma unroll
        for (int o = 0; o < 2; ++o) {
            f32x4 a = ldb4(bf2, o, lgr);
#pragma unroll
            for (int kt = 0; kt < 4; ++kt) a = MFMA16(wf2t[o][kt], o1b[kt], a);
            o2b[o] = cvt_relu(a);
        }
        float b3 = bf3[0];
        f32x4 p = (f32x4){b3, b3, b3, b3};
        p = MFMA16(wf3t[0], o2b[0], p);
        p = MFMA16(wf3t[1], o2b[1], p);
        if (lgr == 0) out[r0 + lcol] = p[0];
    }
}

extern "C" void kernel_launch(void* const* d_in, const int* in_sizes, int n_in,
                              void* d_out, int out_size, void* d_ws, size_t ws_size,
                              hipStream_t stream) {
    (void)in_sizes; (void)n_in; (void)d_ws; (void)ws_size; (void)out_size;
    const float* src = (const float*)d_in[0];
    const float* eps = (const float*)d_in[1];
    const float* Wx1 = (const float*)d_in[2];
    const float* bx1 = (const float*)d_in[3];
    const float* Wx2 = (const float*)d_in[4];
    const float* bx2 = (const float*)d_in[5];
    const float* Wz  = (const float*)d_in[6];
    const float* bz  = (const float*)d_in[7];
    const float* We1 = (const float*)d_in[8];
    const float* be1 = (const float*)d_in[9];
    const float* We2 = (const float*)d_in[10];
    const float* be2 = (const float*)d_in[11];
    const float* Wem = (const float*)d_in[12];
    const float* bem = (const float*)d_in[13];
    const float* Wes = (const float*)d_in[14];
    const float* bes = (const float*)d_in[15];
    const float* Wih = (const float*)d_in[16];
    const float* Whh = (const float*)d_in[17];
    const float* Wf1 = (const float*)d_in[18];
    const float* bf1 = (const float*)d_in[19];
    const float* Wf2 = (const float*)d_in[20];
    const float* bf2 = (const float*)d_in[21];
    const float* Wf3 = (const float*)d_in[22];
    const float* bf3 = (const float*)d_in[23];
    float* out = (float*)d_out;

    hipLaunchKernelGGL(vrnn_kernel, dim3(BB / 16), dim3(256), 0, stream,
                       src, eps, Wx1, bx1, Wx2, bx2, Wz, bz, We1, be1, We2, be2,
                       Wem, bem, Wes, bes, Wih, Whh, Wf1, bf1, Wf2, bf2, Wf3, bf3, out);
}